// Round 10
// baseline (50.694 us; speedup 1.0000x reference)
//
#include <hip/hip_runtime.h>
#include <hip/hip_fp16.h>
#include <math.h>

// Problem constants
#define IMN   256
#define KDIM  512
#define JT    6
#define LTAB  1024
#define MPTS  65536
#define NB    2
#define NC    8
#define NIMG  (NB*NC)
#define KC    (512.0f / 6.283185307179586f)   // K/(2*pi)

#define NBINS 2048          // 2 batches x 32x32 tiles of 16x16 cells
#define CAP   192           // max points per bin (Poisson(64), ~16 sigma)
#define SLAB  21            // stencil rows/cols per bin: 16 + 6 - 1
#define CSTR  5             // slab cell stride in uint2 (4 data + 1 pad)

// ---------------------------------------------------------------------------
// complex helpers + radix-8 FFT
// ---------------------------------------------------------------------------
__device__ __forceinline__ float2 cadd(float2 a, float2 b){ return make_float2(a.x+b.x, a.y+b.y); }
__device__ __forceinline__ float2 csub(float2 a, float2 b){ return make_float2(a.x-b.x, a.y-b.y); }
__device__ __forceinline__ float2 cmul(float2 a, float2 b){ return make_float2(a.x*b.x - a.y*b.y, a.x*b.y + a.y*b.x); }
__device__ __forceinline__ float2 mulnegi(float2 a){ return make_float2(a.y, -a.x); }

__device__ __forceinline__ void dft8(float2 a[8]) {
    const float C = 0.70710678118654752f;
    float2 t0 = cadd(a[0], a[4]);
    float2 t1 = csub(a[0], a[4]);
    float2 t2 = cadd(a[2], a[6]);
    float2 t3 = mulnegi(csub(a[2], a[6]));
    float2 t4 = cadd(a[1], a[5]);
    float2 t5 = csub(a[1], a[5]);
    float2 t6 = cadd(a[3], a[7]);
    float2 t7 = mulnegi(csub(a[3], a[7]));
    float2 E0 = cadd(t0, t2), E2 = csub(t0, t2);
    float2 E1 = cadd(t1, t3), E3 = csub(t1, t3);
    float2 O0 = cadd(t4, t6), O2 = csub(t4, t6);
    float2 O1 = cadd(t5, t7), O3 = csub(t5, t7);
    O1 = make_float2(C*(O1.x + O1.y), C*(O1.y - O1.x));
    O2 = mulnegi(O2);
    O3 = make_float2(C*(O3.y - O3.x), -C*(O3.x + O3.y));
    a[0] = cadd(E0, O0); a[4] = csub(E0, O0);
    a[1] = cadd(E1, O1); a[5] = csub(E1, O1);
    a[2] = cadd(E2, O2); a[6] = csub(E2, O2);
    a[3] = cadd(E3, O3); a[7] = csub(E3, O3);
}

// 512-pt FFT, radix-8^3; natural-order in (n=u+64j in a[j]) and out
// (k=u+64k2 in a[k2]). 2 __syncthreads inside — call block-uniformly.
__device__ __forceinline__ void fft512_r8(float2 a[8], float2* ldsb, int u)
{
    const float A64  = -0.09817477042468103f;    // -2pi/64
    const float A512 = -0.012271846303085129f;   // -2pi/512
    int n0 = u & 7, n1 = u >> 3;

    dft8(a);
    {
        float sw, cw;
        __sincosf(A64 * (float)n1, &sw, &cw);
        float2 step = make_float2(cw, sw);
        float2 w = step;
        #pragma unroll
        for (int k = 1; k < 8; ++k) { a[k] = cmul(a[k], w); w = cmul(w, step); }
    }
    #pragma unroll
    for (int k = 0; k < 8; ++k) ldsb[n0*65 + n1*8 + k] = a[k];
    __syncthreads();

    int k0 = u >> 3;
    #pragma unroll
    for (int n = 0; n < 8; ++n) a[n] = ldsb[n0*65 + n*8 + k0];
    dft8(a);
    {
        float sw, cw;
        __sincosf(A512 * (float)(n0*k0), &sw, &cw);
        float2 w = make_float2(cw, sw);
        __sincosf(A64 * (float)n0, &sw, &cw);
        float2 step = make_float2(cw, sw);
        #pragma unroll
        for (int k = 0; k < 8; ++k) { a[k] = cmul(a[k], w); w = cmul(w, step); }
    }
    #pragma unroll
    for (int k = 0; k < 8; ++k) ldsb[n0*65 + k*8 + k0] = a[k];
    __syncthreads();

    int kk0 = u & 7, kk1 = u >> 3;
    #pragma unroll
    for (int n = 0; n < 8; ++n) a[n] = ldsb[n*65 + kk1*8 + kk0];
    dft8(a);
}

// Single source of truth for the tap window base (explicit fmaf, bit-exact
// at every call site). Taps are ik+1 .. ik+6.
__device__ __forceinline__ int tap_base(float om) {
    return (int)floorf(fmaf(om, KC, -3.0f));
}

// 16x16-cell tiles: bin = (b, cell0>>4, cell1>>4)
__device__ __forceinline__ int point_bin(float om0, float om1, int b) {
    int cell0 = (tap_base(om0) + 3) & (KDIM - 1);
    int cell1 = (tap_base(om1) + 3) & (KDIM - 1);
    return (b << 10) | ((cell0 >> 4) << 5) | (cell1 >> 4);
}

// ---------------------------------------------------------------------------
// Fused kernel: blocks 0..511 = column FFTs (apodization fused, writes FP16
// tmp[ic][kr][col]); blocks 512..767 = binscatter (LDS-private histogram).
// ---------------------------------------------------------------------------
__global__ __launch_bounds__(512) void fused_cols_bin(
    const float* __restrict__ x, const float* __restrict__ smap,
    const float* __restrict__ sn, __half2* __restrict__ tmp,
    const float* __restrict__ om, int* __restrict__ counts,
    float2* __restrict__ spts, int* __restrict__ pos)
{
    __shared__ float2 smem[8 * 520];           // 33.3 KB, unioned
    int t = threadIdx.x;

    if (blockIdx.x < 512) {
        // ---- fft_cols ----
        int fid = blockIdx.x;
        int ic = fid >> 5, ctile = fid & 31;
        int b = ic >> 3, c = ic & 7;
        int f = t & 7, u = t >> 3;
        int col = ctile * 8 + f;

        float2 a[8];
        #pragma unroll
        for (int j = 0; j < 4; ++j) {
            int r = u + 64*j;
            int pix = r * IMN + col;
            float xr = x[(b*2 + 0)*(IMN*IMN) + pix];
            float xi = x[(b*2 + 1)*(IMN*IMN) + pix];
            float sr = smap[((b*NC + c)*2 + 0)*(IMN*IMN) + pix];
            float si = smap[((b*NC + c)*2 + 1)*(IMN*IMN) + pix];
            float s  = sn[pix] * (1.0f/512.0f);
            a[j] = make_float2((xr*sr - xi*si)*s, (xr*si + xi*sr)*s);
        }
        #pragma unroll
        for (int j = 4; j < 8; ++j) a[j] = make_float2(0.f, 0.f);

        fft512_r8(a, &smem[f * 520], u);

        __half2* ocol = tmp + (size_t)ic * KDIM * IMN + col;
        #pragma unroll
        for (int k2 = 0; k2 < 8; ++k2)
            ocol[(size_t)(u + 64*k2) * IMN] = __floats2half2_rn(a[k2].x, a[k2].y);
    } else {
        // ---- binscatter ----
        int* hist = (int*)smem;
        int* base = hist + NBINS;
        #pragma unroll
        for (int k = 0; k < 4; ++k) hist[t + k*512] = 0;
        __syncthreads();

        int gt = (blockIdx.x - 512) * 512 + t;   // 0..131071
        int m  = gt & (MPTS - 1);
        int b  = gt >> 16;
        float om0 = om[(b*2 + 0) * MPTS + m];
        float om1 = om[(b*2 + 1) * MPTS + m];
        int bin = point_bin(om0, om1, b);
        int r = atomicAdd(&hist[bin], 1);
        __syncthreads();

        #pragma unroll
        for (int k = 0; k < 4; ++k) {
            int i = t + k*512;
            int cnt = hist[i];
            base[i] = cnt ? atomicAdd(&counts[i], cnt) : 0;
        }
        __syncthreads();

        int slot = base[bin] + r;
        if (slot < CAP) {
            spts[(size_t)bin * CAP + slot] = make_float2(om0, om1);
            pos[gt] = bin * CAP + slot;
        } else {
            pos[gt] = bin * CAP;               // statistically unreachable
        }
    }
}

// ---------------------------------------------------------------------------
// Row FFTs: 8 coils of one (b,kr) per block; reads FP16 tmp, writes
// coil-interleaved FP16 grid gridH[b][kr][kc][coil].
// ---------------------------------------------------------------------------
__global__ __launch_bounds__(512) void fft_rows(
    const __half2* __restrict__ tmp, __half2* __restrict__ gridH)
{
    __shared__ float2 lds[8 * 520];
    int t = threadIdx.x;
    int f = t & 7, u = t >> 3;                 // f = coil
    int kr = blockIdx.x;
    int b  = blockIdx.y;

    const __half2* irow = tmp + ((size_t)(b*NC + f) * KDIM + kr) * IMN;
    float2 a[8];
    #pragma unroll
    for (int j = 0; j < 4; ++j) a[j] = __half22float2(irow[u + 64*j]);
    #pragma unroll
    for (int j = 4; j < 8; ++j) a[j] = make_float2(0.f, 0.f);

    fft512_r8(a, &lds[f * 520], u);

    __half2* obase = gridH + ((size_t)(b * KDIM + kr) * KDIM) * NC + f;
    #pragma unroll
    for (int k2 = 0; k2 < 8; ++k2)
        obase[(size_t)(u + 64*k2) * NC] = __floats2half2_rn(a[k2].x, a[k2].y);
}

// ---------------------------------------------------------------------------
// Interp: per-bin (16x16 cells), LDS fp16 slab with padded cell stride
// (CSTR=5 uint2, bank-spread). 4 threads/point, 2 coils each (uint2/tap).
// Inner j-sum packed __hfma2, outer ii-sum fp32. Coalesced uint2 staged out.
// ---------------------------------------------------------------------------
__global__ __launch_bounds__(256) void interp10(
    const uint4* __restrict__ gridU,   // [b][kr][kc][2 x uint4]
    const float2* __restrict__ spts, const int* __restrict__ counts,
    const float* __restrict__ tab0, uint2* __restrict__ staged2)
{
    int bid = blockIdx.x;
    int bin = (bid & 7) * (NBINS / 8) + (bid >> 3);   // XCD-chunked, bijective

    int count = counts[bin];
    if (count > CAP) count = CAP;
    if (count == 0) return;

    int b    = bin >> 10;
    int tile = bin & 1023;
    int r0   = (tile >> 5) << 4;       // tile base row (cell coords)
    int c0   = (tile & 31) << 4;       // tile base col

    __shared__ uint2 slab2[SLAB * SLAB * CSTR];   // 21*21*5*8 = 17.6 KB

    const uint4* plane = gridU + (size_t)b * KDIM * KDIM * 2;
    int t = threadIdx.x;

    // stage: each iter loads one uint4 (coil-pair-pair) and writes 2 uint2
    for (int u = t; u < SLAB * SLAB * 2; u += 256) {
        int cell = u >> 1;
        int pair = u & 1;                  // 0 -> q0,q1 ; 1 -> q2,q3
        int cr   = cell / SLAB;
        int cc   = cell - cr * SLAB;
        int gr   = (r0 - 2 + cr) & (KDIM - 1);
        int gc   = (c0 - 2 + cc) & (KDIM - 1);
        uint4 v = plane[((size_t)gr * KDIM + gc) * 2 + pair];
        int sbase = cell * CSTR + pair * 2;
        slab2[sbase]     = make_uint2(v.x, v.y);
        slab2[sbase + 1] = make_uint2(v.z, v.w);
    }
    __syncthreads();

    int q  = t & 3;                    // coil pair: coils 2q, 2q+1
    int pi = t >> 2;                   // point-within-chunk 0..63

    for (int p0 = 0; p0 < count; p0 += 64) {
        int idx = p0 + pi;
        if (idx < count) {
            float2 sp = spts[(size_t)bin * CAP + idx];
            float om0 = sp.x, om1 = sp.y;

            float   w0f[6];
            __half2 w1h[6];
            int     l0[6], l1[6];
            {
                float tm = om0 * KC;
                int   ik = tap_base(om0);
                int cell = (ik + 3) & (KDIM - 1);
                int lbase = cell - r0;             // 0..15
                #pragma unroll
                for (int j = 0; j < 6; ++j) {
                    float dist = tm - (float)(ik + j + 1);
                    int tidx = (int)rintf((dist + 3.0f) * 1024.0f);
                    tidx = tidx < 0 ? 0 : (tidx > JT*LTAB ? JT*LTAB : tidx);
                    w0f[j] = tab0[tidx];
                    l0[j] = lbase + j;             // slab-local 0..20
                }
            }
            {
                float tm = om1 * KC;
                int   ik = tap_base(om1);
                int cell = (ik + 3) & (KDIM - 1);
                int lbase = cell - c0;
                #pragma unroll
                for (int j = 0; j < 6; ++j) {
                    float dist = tm - (float)(ik + j + 1);
                    int tidx = (int)rintf((dist + 3.0f) * 1024.0f);
                    tidx = tidx < 0 ? 0 : (tidx > JT*LTAB ? JT*LTAB : tidx);
                    w1h[j] = __float2half2_rn(tab0[tidx]);   // tab1 == tab0
                    l1[j] = lbase + j;
                }
            }

            float2 acc0 = make_float2(0.f,0.f), acc1 = make_float2(0.f,0.f);
            #pragma unroll
            for (int ii = 0; ii < 6; ++ii) {
                int rowb = l0[ii] * SLAB;
                __half2 s0 = __half2half2(__float2half(0.f));
                __half2 s1 = s0;
                #pragma unroll
                for (int j = 0; j < 6; ++j) {
                    uint2 v = slab2[(rowb + l1[j]) * CSTR + q];
                    const __half2* h = (const __half2*)&v;
                    s0 = __hfma2(w1h[j], h[0], s0);
                    s1 = __hfma2(w1h[j], h[1], s1);
                }
                float wi = w0f[ii];
                float2 f0 = __half22float2(s0);
                float2 f1 = __half22float2(s1);
                acc0.x = fmaf(wi, f0.x, acc0.x); acc0.y = fmaf(wi, f0.y, acc0.y);
                acc1.x = fmaf(wi, f1.x, acc1.x); acc1.y = fmaf(wi, f1.y, acc1.y);
            }

            float ph = (om0 + om1) * 128.0f;
            float spn, cpn;
            __sincosf(ph, &spn, &cpn);

            uint2 o;
            __half2* oh = (__half2*)&o;
            oh[0] = __floats2half2_rn(acc0.x*cpn - acc0.y*spn, acc0.x*spn + acc0.y*cpn);
            oh[1] = __floats2half2_rn(acc1.x*cpn - acc1.y*spn, acc1.x*spn + acc1.y*cpn);
            staged2[((size_t)bin * CAP + idx) * 4 + q] = o;
        }
    }
}

// ---------------------------------------------------------------------------
// Unpermute: one thread per (b,m); reads its point's 32B staged record and
// writes out coalesced (m lane-consecutive, f32).
// ---------------------------------------------------------------------------
__global__ __launch_bounds__(256) void unpermute(
    const uint4* __restrict__ stagedU, const int* __restrict__ pos,
    float* __restrict__ out)
{
    int gt = blockIdx.x * 256 + threadIdx.x;   // 0..131071
    int m  = gt & (MPTS - 1);
    int b  = gt >> 16;
    int p  = pos[gt];

    uint4 v0 = stagedU[(size_t)p * 2 + 0];     // coils 0..3
    uint4 v1 = stagedU[(size_t)p * 2 + 1];     // coils 4..7
    const __half2* h0 = (const __half2*)&v0;
    const __half2* h1 = (const __half2*)&v1;

    size_t base = (size_t)b * (NC * 2 * MPTS) + m;
    #pragma unroll
    for (int k = 0; k < 4; ++k) {
        float2 f = __half22float2(h0[k]);
        out[base + (2*k + 0)*MPTS] = f.x;
        out[base + (2*k + 1)*MPTS] = f.y;
    }
    #pragma unroll
    for (int k = 0; k < 4; ++k) {
        float2 f = __half22float2(h1[k]);
        out[base + (2*(k+4) + 0)*MPTS] = f.x;
        out[base + (2*(k+4) + 1)*MPTS] = f.y;
    }
}

// ---------------------------------------------------------------------------
extern "C" void kernel_launch(void* const* d_in, const int* in_sizes, int n_in,
                              void* d_out, int out_size, void* d_ws, size_t ws_size,
                              hipStream_t stream) {
    const float* x    = (const float*)d_in[0];
    const float* smap = (const float*)d_in[1];
    const float* om   = (const float*)d_in[2];
    const float* sn   = (const float*)d_in[3];
    const float* tab0 = (const float*)d_in[4];
    float* out = (float*)d_out;

    // ws layout:
    // [0,   16MB)          gridH  (2*512*512*8 half2 = 16 MB)
    // [16MB,24.4MB)        tmp    (16*512*256 half2 = 8.4 MB)
    // [25MB, +8KB)         counts (2048 int)
    // [25MB+64KB, +3.1MB)  spts   (2048*192 float2)
    // [29MB, +512KB)       pos    (131072 int)
    // [32MB, +12.6MB)      staged (2048*192*4 uint2)
    char* ws = (char*)d_ws;
    __half2* gridH  = (__half2*)(ws);
    __half2* tmp    = (__half2*)(ws + (size_t)16*1024*1024);
    int*     counts = (int*)    (ws + (size_t)25*1024*1024);
    float2*  spts   = (float2*) (ws + (size_t)25*1024*1024 + 65536);
    int*     pos    = (int*)    (ws + (size_t)29*1024*1024);
    uint2*   staged2= (uint2*)  (ws + (size_t)32*1024*1024);

    hipMemsetAsync(counts, 0, NBINS * sizeof(int), stream);

    fused_cols_bin<<<768, 512, 0, stream>>>(x, smap, sn, tmp,
                                            om, counts, spts, pos);

    dim3 g2(KDIM, NB);                 // 512 x 2
    fft_rows<<<g2, 512, 0, stream>>>(tmp, gridH);

    interp10<<<NBINS, 256, 0, stream>>>((const uint4*)gridH, spts, counts,
                                        tab0, staged2);

    unpermute<<<(NB*MPTS)/256, 256, 0, stream>>>((const uint4*)staged2, pos, out);
}

// Round 11
// 49.278 us; speedup vs baseline: 1.0287x; 1.0287x over previous
//
#include <hip/hip_runtime.h>
#include <hip/hip_fp16.h>
#include <math.h>

// Problem constants
#define IMN   256
#define KDIM  512
#define JT    6
#define LTAB  1024
#define MPTS  65536
#define NB    2
#define NC    8
#define NIMG  (NB*NC)
#define KC    (512.0f / 6.283185307179586f)   // K/(2*pi)

#define NBINS 2048          // 2 batches x 32x32 tiles of 16x16 cells
#define CAP   192           // max points per bin (Poisson(64), ~16 sigma)
#define SLAB  21            // stencil rows/cols per bin: 16 + 6 - 1

// ---------------------------------------------------------------------------
// complex helpers + radix-8 FFT
// ---------------------------------------------------------------------------
__device__ __forceinline__ float2 cadd(float2 a, float2 b){ return make_float2(a.x+b.x, a.y+b.y); }
__device__ __forceinline__ float2 csub(float2 a, float2 b){ return make_float2(a.x-b.x, a.y-b.y); }
__device__ __forceinline__ float2 cmul(float2 a, float2 b){ return make_float2(a.x*b.x - a.y*b.y, a.x*b.y + a.y*b.x); }
__device__ __forceinline__ float2 mulnegi(float2 a){ return make_float2(a.y, -a.x); }

__device__ __forceinline__ void dft8(float2 a[8]) {
    const float C = 0.70710678118654752f;
    float2 t0 = cadd(a[0], a[4]);
    float2 t1 = csub(a[0], a[4]);
    float2 t2 = cadd(a[2], a[6]);
    float2 t3 = mulnegi(csub(a[2], a[6]));
    float2 t4 = cadd(a[1], a[5]);
    float2 t5 = csub(a[1], a[5]);
    float2 t6 = cadd(a[3], a[7]);
    float2 t7 = mulnegi(csub(a[3], a[7]));
    float2 E0 = cadd(t0, t2), E2 = csub(t0, t2);
    float2 E1 = cadd(t1, t3), E3 = csub(t1, t3);
    float2 O0 = cadd(t4, t6), O2 = csub(t4, t6);
    float2 O1 = cadd(t5, t7), O3 = csub(t5, t7);
    O1 = make_float2(C*(O1.x + O1.y), C*(O1.y - O1.x));
    O2 = mulnegi(O2);
    O3 = make_float2(C*(O3.y - O3.x), -C*(O3.x + O3.y));
    a[0] = cadd(E0, O0); a[4] = csub(E0, O0);
    a[1] = cadd(E1, O1); a[5] = csub(E1, O1);
    a[2] = cadd(E2, O2); a[6] = csub(E2, O2);
    a[3] = cadd(E3, O3); a[7] = csub(E3, O3);
}

// 512-pt FFT, radix-8^3; natural-order in (n=u+64j in a[j]) and out
// (k=u+64k2 in a[k2]). 2 __syncthreads inside — call block-uniformly.
__device__ __forceinline__ void fft512_r8(float2 a[8], float2* ldsb, int u)
{
    const float A64  = -0.09817477042468103f;    // -2pi/64
    const float A512 = -0.012271846303085129f;   // -2pi/512
    int n0 = u & 7, n1 = u >> 3;

    dft8(a);
    {
        float sw, cw;
        __sincosf(A64 * (float)n1, &sw, &cw);
        float2 step = make_float2(cw, sw);
        float2 w = step;
        #pragma unroll
        for (int k = 1; k < 8; ++k) { a[k] = cmul(a[k], w); w = cmul(w, step); }
    }
    #pragma unroll
    for (int k = 0; k < 8; ++k) ldsb[n0*65 + n1*8 + k] = a[k];
    __syncthreads();

    int k0 = u >> 3;
    #pragma unroll
    for (int n = 0; n < 8; ++n) a[n] = ldsb[n0*65 + n*8 + k0];
    dft8(a);
    {
        float sw, cw;
        __sincosf(A512 * (float)(n0*k0), &sw, &cw);
        float2 w = make_float2(cw, sw);
        __sincosf(A64 * (float)n0, &sw, &cw);
        float2 step = make_float2(cw, sw);
        #pragma unroll
        for (int k = 0; k < 8; ++k) { a[k] = cmul(a[k], w); w = cmul(w, step); }
    }
    #pragma unroll
    for (int k = 0; k < 8; ++k) ldsb[n0*65 + k*8 + k0] = a[k];
    __syncthreads();

    int kk0 = u & 7, kk1 = u >> 3;
    #pragma unroll
    for (int n = 0; n < 8; ++n) a[n] = ldsb[n*65 + kk1*8 + kk0];
    dft8(a);
}

// Single source of truth for the tap window base (explicit fmaf, bit-exact
// at every call site). Taps are ik+1 .. ik+6.
__device__ __forceinline__ int tap_base(float om) {
    return (int)floorf(fmaf(om, KC, -3.0f));
}

// 16x16-cell tiles: bin = (b, cell0>>4, cell1>>4)
__device__ __forceinline__ int point_bin(float om0, float om1, int b) {
    int cell0 = (tap_base(om0) + 3) & (KDIM - 1);
    int cell1 = (tap_base(om1) + 3) & (KDIM - 1);
    return (b << 10) | ((cell0 >> 4) << 5) | (cell1 >> 4);
}

// ---------------------------------------------------------------------------
// Fused kernel: blocks 0..511 = column FFTs (apodization fused, writes FP16
// tmp[ic][kr][col]); blocks 512..767 = binscatter (LDS-private histogram).
// ---------------------------------------------------------------------------
__global__ __launch_bounds__(512) void fused_cols_bin(
    const float* __restrict__ x, const float* __restrict__ smap,
    const float* __restrict__ sn, __half2* __restrict__ tmp,
    const float* __restrict__ om, int* __restrict__ counts,
    float2* __restrict__ spts, int* __restrict__ pos)
{
    __shared__ float2 smem[8 * 520];           // 33.3 KB, unioned
    int t = threadIdx.x;

    if (blockIdx.x < 512) {
        // ---- fft_cols ----
        int fid = blockIdx.x;
        int ic = fid >> 5, ctile = fid & 31;
        int b = ic >> 3, c = ic & 7;
        int f = t & 7, u = t >> 3;
        int col = ctile * 8 + f;

        float2 a[8];
        #pragma unroll
        for (int j = 0; j < 4; ++j) {
            int r = u + 64*j;
            int pix = r * IMN + col;
            float xr = x[(b*2 + 0)*(IMN*IMN) + pix];
            float xi = x[(b*2 + 1)*(IMN*IMN) + pix];
            float sr = smap[((b*NC + c)*2 + 0)*(IMN*IMN) + pix];
            float si = smap[((b*NC + c)*2 + 1)*(IMN*IMN) + pix];
            float s  = sn[pix] * (1.0f/512.0f);
            a[j] = make_float2((xr*sr - xi*si)*s, (xr*si + xi*sr)*s);
        }
        #pragma unroll
        for (int j = 4; j < 8; ++j) a[j] = make_float2(0.f, 0.f);

        fft512_r8(a, &smem[f * 520], u);

        __half2* ocol = tmp + (size_t)ic * KDIM * IMN + col;
        #pragma unroll
        for (int k2 = 0; k2 < 8; ++k2)
            ocol[(size_t)(u + 64*k2) * IMN] = __floats2half2_rn(a[k2].x, a[k2].y);
    } else {
        // ---- binscatter ----
        int* hist = (int*)smem;
        int* base = hist + NBINS;
        #pragma unroll
        for (int k = 0; k < 4; ++k) hist[t + k*512] = 0;
        __syncthreads();

        int gt = (blockIdx.x - 512) * 512 + t;   // 0..131071
        int m  = gt & (MPTS - 1);
        int b  = gt >> 16;
        float om0 = om[(b*2 + 0) * MPTS + m];
        float om1 = om[(b*2 + 1) * MPTS + m];
        int bin = point_bin(om0, om1, b);
        int r = atomicAdd(&hist[bin], 1);
        __syncthreads();

        #pragma unroll
        for (int k = 0; k < 4; ++k) {
            int i = t + k*512;
            int cnt = hist[i];
            base[i] = cnt ? atomicAdd(&counts[i], cnt) : 0;
        }
        __syncthreads();

        int slot = base[bin] + r;
        if (slot < CAP) {
            spts[(size_t)bin * CAP + slot] = make_float2(om0, om1);
            pos[gt] = bin * CAP + slot;
        } else {
            pos[gt] = bin * CAP;               // statistically unreachable
        }
    }
}

// ---------------------------------------------------------------------------
// Row FFTs: 8 coils of one (b,kr) per block; reads FP16 tmp, writes
// coil-interleaved FP16 grid gridH[b][kr][kc][coil].
// ---------------------------------------------------------------------------
__global__ __launch_bounds__(512) void fft_rows(
    const __half2* __restrict__ tmp, __half2* __restrict__ gridH)
{
    __shared__ float2 lds[8 * 520];
    int t = threadIdx.x;
    int f = t & 7, u = t >> 3;                 // f = coil
    int kr = blockIdx.x;
    int b  = blockIdx.y;

    const __half2* irow = tmp + ((size_t)(b*NC + f) * KDIM + kr) * IMN;
    float2 a[8];
    #pragma unroll
    for (int j = 0; j < 4; ++j) a[j] = __half22float2(irow[u + 64*j]);
    #pragma unroll
    for (int j = 4; j < 8; ++j) a[j] = make_float2(0.f, 0.f);

    fft512_r8(a, &lds[f * 520], u);

    __half2* obase = gridH + ((size_t)(b * KDIM + kr) * KDIM) * NC + f;
    #pragma unroll
    for (int k2 = 0; k2 < 8; ++k2)
        obase[(size_t)(u + 64*k2) * NC] = __floats2half2_rn(a[k2].x, a[k2].y);
}

// ---------------------------------------------------------------------------
// Interp: per-bin (16x16 cells), LDS fp16 slab (14.1 KB). 2 threads/point,
// 4 coils each. Inner j-sum via packed __hfma2 (5 ops/tap), outer ii-sum in
// fp32. Coalesced fp16 staged output.
// ---------------------------------------------------------------------------
__global__ __launch_bounds__(256) void interp9(
    const uint4* __restrict__ gridU,   // [b][kr][kc][2 x uint4]
    const float2* __restrict__ spts, const int* __restrict__ counts,
    const float* __restrict__ tab0, uint4* __restrict__ stagedU)
{
    int bid = blockIdx.x;
    int bin = (bid & 7) * (NBINS / 8) + (bid >> 3);   // XCD-chunked, bijective

    int count = counts[bin];
    if (count > CAP) count = CAP;
    if (count == 0) return;

    int b    = bin >> 10;
    int tile = bin & 1023;
    int r0   = (tile >> 5) << 4;       // tile base row (cell coords)
    int c0   = (tile & 31) << 4;       // tile base col

    __shared__ uint4 slab[SLAB * SLAB * 2];    // 14.1 KB

    const uint4* plane = gridU + (size_t)b * KDIM * KDIM * 2;
    int t = threadIdx.x;

    for (int u = t; u < SLAB * SLAB * 2; u += 256) {
        int cell = u >> 1;
        int qq   = u & 1;
        int cr   = cell / SLAB;
        int cc   = cell - cr * SLAB;
        int gr   = (r0 - 2 + cr) & (KDIM - 1);
        int gc   = (c0 - 2 + cc) & (KDIM - 1);
        slab[u] = plane[((size_t)gr * KDIM + gc) * 2 + qq];
    }
    __syncthreads();

    int q  = t & 1;                    // coil quad: 0 -> coils 0..3, 1 -> 4..7
    int pi = t >> 1;                   // point-within-chunk 0..127

    for (int p0 = 0; p0 < count; p0 += 128) {
        int idx = p0 + pi;
        if (idx < count) {
            float2 sp = spts[(size_t)bin * CAP + idx];
            float om0 = sp.x, om1 = sp.y;

            float   w0f[6];
            __half2 w1h[6];
            int     l0[6], l1[6];
            {
                float tm = om0 * KC;
                int   ik = tap_base(om0);
                int cell = (ik + 3) & (KDIM - 1);
                int lbase = cell - r0;             // 0..15
                #pragma unroll
                for (int j = 0; j < 6; ++j) {
                    float dist = tm - (float)(ik + j + 1);
                    int tidx = (int)rintf((dist + 3.0f) * 1024.0f);
                    tidx = tidx < 0 ? 0 : (tidx > JT*LTAB ? JT*LTAB : tidx);
                    w0f[j] = tab0[tidx];
                    l0[j] = lbase + j;             // slab-local 0..20
                }
            }
            {
                float tm = om1 * KC;
                int   ik = tap_base(om1);
                int cell = (ik + 3) & (KDIM - 1);
                int lbase = cell - c0;
                #pragma unroll
                for (int j = 0; j < 6; ++j) {
                    float dist = tm - (float)(ik + j + 1);
                    int tidx = (int)rintf((dist + 3.0f) * 1024.0f);
                    tidx = tidx < 0 ? 0 : (tidx > JT*LTAB ? JT*LTAB : tidx);
                    w1h[j] = __float2half2_rn(tab0[tidx]);   // tab1 == tab0
                    l1[j] = lbase + j;
                }
            }

            float2 acc0 = make_float2(0.f,0.f), acc1 = make_float2(0.f,0.f);
            float2 acc2 = make_float2(0.f,0.f), acc3 = make_float2(0.f,0.f);
            #pragma unroll
            for (int ii = 0; ii < 6; ++ii) {
                int rowb = l0[ii] * SLAB;
                __half2 s0 = __half2half2(__float2half(0.f));
                __half2 s1 = s0, s2 = s0, s3 = s0;
                #pragma unroll
                for (int j = 0; j < 6; ++j) {
                    uint4 v = slab[(rowb + l1[j]) * 2 + q];
                    const __half2* h = (const __half2*)&v;
                    s0 = __hfma2(w1h[j], h[0], s0);
                    s1 = __hfma2(w1h[j], h[1], s1);
                    s2 = __hfma2(w1h[j], h[2], s2);
                    s3 = __hfma2(w1h[j], h[3], s3);
                }
                float wi = w0f[ii];
                float2 f0 = __half22float2(s0);
                float2 f1 = __half22float2(s1);
                float2 f2 = __half22float2(s2);
                float2 f3 = __half22float2(s3);
                acc0.x = fmaf(wi, f0.x, acc0.x); acc0.y = fmaf(wi, f0.y, acc0.y);
                acc1.x = fmaf(wi, f1.x, acc1.x); acc1.y = fmaf(wi, f1.y, acc1.y);
                acc2.x = fmaf(wi, f2.x, acc2.x); acc2.y = fmaf(wi, f2.y, acc2.y);
                acc3.x = fmaf(wi, f3.x, acc3.x); acc3.y = fmaf(wi, f3.y, acc3.y);
            }

            float ph = (om0 + om1) * 128.0f;
            float spn, cpn;
            __sincosf(ph, &spn, &cpn);

            uint4 o;
            __half2* oh = (__half2*)&o;
            oh[0] = __floats2half2_rn(acc0.x*cpn - acc0.y*spn, acc0.x*spn + acc0.y*cpn);
            oh[1] = __floats2half2_rn(acc1.x*cpn - acc1.y*spn, acc1.x*spn + acc1.y*cpn);
            oh[2] = __floats2half2_rn(acc2.x*cpn - acc2.y*spn, acc2.x*spn + acc2.y*cpn);
            oh[3] = __floats2half2_rn(acc3.x*cpn - acc3.y*spn, acc3.x*spn + acc3.y*cpn);
            stagedU[((size_t)bin * CAP + idx) * 2 + q] = o;
        }
    }
}

// ---------------------------------------------------------------------------
// Unpermute: one thread per (b,m); reads its point's 32B staged record and
// writes out coalesced (m lane-consecutive, f32).
// ---------------------------------------------------------------------------
__global__ __launch_bounds__(256) void unpermute(
    const uint4* __restrict__ stagedU, const int* __restrict__ pos,
    float* __restrict__ out)
{
    int gt = blockIdx.x * 256 + threadIdx.x;   // 0..131071
    int m  = gt & (MPTS - 1);
    int b  = gt >> 16;
    int p  = pos[gt];

    uint4 v0 = stagedU[(size_t)p * 2 + 0];     // coils 0..3
    uint4 v1 = stagedU[(size_t)p * 2 + 1];     // coils 4..7
    const __half2* h0 = (const __half2*)&v0;
    const __half2* h1 = (const __half2*)&v1;

    size_t base = (size_t)b * (NC * 2 * MPTS) + m;
    #pragma unroll
    for (int k = 0; k < 4; ++k) {
        float2 f = __half22float2(h0[k]);
        out[base + (2*k + 0)*MPTS] = f.x;
        out[base + (2*k + 1)*MPTS] = f.y;
    }
    #pragma unroll
    for (int k = 0; k < 4; ++k) {
        float2 f = __half22float2(h1[k]);
        out[base + (2*(k+4) + 0)*MPTS] = f.x;
        out[base + (2*(k+4) + 1)*MPTS] = f.y;
    }
}

// ---------------------------------------------------------------------------
extern "C" void kernel_launch(void* const* d_in, const int* in_sizes, int n_in,
                              void* d_out, int out_size, void* d_ws, size_t ws_size,
                              hipStream_t stream) {
    const float* x    = (const float*)d_in[0];
    const float* smap = (const float*)d_in[1];
    const float* om   = (const float*)d_in[2];
    const float* sn   = (const float*)d_in[3];
    const float* tab0 = (const float*)d_in[4];
    float* out = (float*)d_out;

    // ws layout:
    // [0,   16MB)          gridH  (2*512*512*8 half2 = 16 MB)
    // [16MB,24.4MB)        tmp    (16*512*256 half2 = 8.4 MB)
    // [25MB, +8KB)         counts (2048 int)
    // [25MB+64KB, +3.1MB)  spts   (2048*192 float2)
    // [29MB, +512KB)       pos    (131072 int)
    // [32MB, +12.6MB)      staged (2048*192*2 uint4)
    char* ws = (char*)d_ws;
    __half2* gridH  = (__half2*)(ws);
    __half2* tmp    = (__half2*)(ws + (size_t)16*1024*1024);
    int*     counts = (int*)    (ws + (size_t)25*1024*1024);
    float2*  spts   = (float2*) (ws + (size_t)25*1024*1024 + 65536);
    int*     pos    = (int*)    (ws + (size_t)29*1024*1024);
    uint4*   stagedU= (uint4*)  (ws + (size_t)32*1024*1024);

    hipMemsetAsync(counts, 0, NBINS * sizeof(int), stream);

    fused_cols_bin<<<768, 512, 0, stream>>>(x, smap, sn, tmp,
                                            om, counts, spts, pos);

    dim3 g2(KDIM, NB);                 // 512 x 2
    fft_rows<<<g2, 512, 0, stream>>>(tmp, gridH);

    interp9<<<NBINS, 256, 0, stream>>>((const uint4*)gridH, spts, counts,
                                       tab0, stagedU);

    unpermute<<<(NB*MPTS)/256, 256, 0, stream>>>(stagedU, pos, out);
}